// Round 7
// baseline (85.284 us; speedup 1.0000x reference)
//
#include <hip/hip_runtime.h>
#include <hip/hip_bf16.h>
#include <stdint.h>

// CrossAttentionHead: B=8,S=2048,D=1024,HS=64, fp32 in/out, bf16 MFMA internally.
// k0: W -> bf16 fragment-swizzled (scale folded into Wq)
// k1: projections — R6: barrier-free per-wave register pipeline.
//     R1-R5 post-mortem: every LDS/barrier-coupled structure pins at ~75us
//     (6 B/cyc/CU staged) because the compute phase (~250cyc at N=64) can't
//     amortize block-lockstep staging bursts. New structure: one 16x64 tile
//     per wave, BK=32, depth-3 register rotation (loads issue 2 steps ahead),
//     no LDS, no barriers -> ~12 loads/wave continuously in flight.
// k2: flash attention, causal, 4-way k-split per q-tile (flash-decoding merge)

#define NB  8
#define SEQ 2048
#define DIM 1024
#define HSZ 64

typedef short bf16x8 __attribute__((ext_vector_type(8)));
typedef short s16x4  __attribute__((ext_vector_type(4)));
typedef float f32x4  __attribute__((ext_vector_type(4)));

__device__ __forceinline__ short f2bf(float f) {
  __hip_bfloat16 h = __float2bfloat16(f);
  return __builtin_bit_cast(short, h);
}

// ---------------- Kernel 0: W -> bf16 B-fragment layout -------------------
// idx = (((w*32 + s)*4 + t)*64 + lane)*8 + i
// val = W[k][n]*scale, k = s*32 + (lane>>4)*8 + i, n = t*16 + (lane&15)
__global__ void w_prep(const float* __restrict__ Wq, const float* __restrict__ Wk,
                       const float* __restrict__ Wv, short* __restrict__ wfrag) {
  const int total = 3 << 16;
  for (int e = blockIdx.x * blockDim.x + threadIdx.x; e < total;
       e += gridDim.x * blockDim.x) {
    int i = e & 7, l = (e >> 3) & 63, t = (e >> 9) & 3, s = (e >> 11) & 31, w = e >> 16;
    const float* W = (w == 0) ? Wq : (w == 1) ? Wk : Wv;
    float scale = (w == 0) ? 0.125f : 1.0f;   // fold HS^-0.5 into Wq
    int k = s * 32 + (l >> 4) * 8 + i;
    int n = t * 16 + (l & 15);
    wfrag[e] = f2bf(W[k * HSZ + n] * scale);
  }
}

// ---------------- Kernel 1: projections -----------------------------------
// grid (256, 3), block 256 (4 waves, each wave = one independent 16x64 tile).
// K=1024 in 32 steps of 32; per step per lane: 2 f32x4 X-loads + 4 bf16x8
// W-frag loads + 4 MFMA. Depth-3 rotation: step s issues loads for s+2.
// No LDS, no barriers — per-wave vmcnt pipelining only.
__global__ __launch_bounds__(256, 4) void proj(const float* __restrict__ Xq,
                                               const float* __restrict__ Xk,
                                               const float* __restrict__ Xv,
                                               const short* __restrict__ wfrag,
                                               short* __restrict__ qb,
                                               short* __restrict__ kbuf,
                                               short* __restrict__ vT) {
  const int tid = threadIdx.x;
  const int wave = tid >> 6, lane = tid & 63;
  const int hi = lane >> 4, lo = lane & 15;
  const int which = blockIdx.y;
  const float* X = (which == 0) ? Xq : (which == 1) ? Xk : Xv;
  const short* wf = wfrag + (which << 16);
  const int row0 = (blockIdx.x * 4 + wave) * 16;
  const float* xp = X + (size_t)(row0 + lo) * DIM + hi * 8;
  const short* wp = wf + lane * 8;

  f32x4  xa[3][2];
  bf16x8 wa[3][4];

#define LOADS(s, slot)                                                         \
  {                                                                            \
    xa[slot][0] = *(const f32x4*)(xp + (s) * 32);                              \
    xa[slot][1] = *(const f32x4*)(xp + (s) * 32 + 4);                          \
    wa[slot][0] = *(const bf16x8*)(wp + (s) * 2048);                           \
    wa[slot][1] = *(const bf16x8*)(wp + (s) * 2048 + 512);                     \
    wa[slot][2] = *(const bf16x8*)(wp + (s) * 2048 + 1024);                    \
    wa[slot][3] = *(const bf16x8*)(wp + (s) * 2048 + 1536);                    \
  }

  LOADS(0, 0);
  LOADS(1, 1);

  f32x4 acc0 = {0.f, 0.f, 0.f, 0.f}, acc1 = acc0, acc2 = acc0, acc3 = acc0;
#pragma unroll
  for (int s = 0; s < 32; ++s) {
    const int slot = s % 3;
    if (s < 30) LOADS(s + 2, (s + 2) % 3);
    const f32x4 a0 = xa[slot][0];
    const f32x4 a1 = xa[slot][1];
    bf16x8 af;
    af[0] = f2bf(a0[0]); af[1] = f2bf(a0[1]); af[2] = f2bf(a0[2]); af[3] = f2bf(a0[3]);
    af[4] = f2bf(a1[0]); af[5] = f2bf(a1[1]); af[6] = f2bf(a1[2]); af[7] = f2bf(a1[3]);
    acc0 = __builtin_amdgcn_mfma_f32_16x16x32_bf16(af, wa[slot][0], acc0, 0, 0, 0);
    acc1 = __builtin_amdgcn_mfma_f32_16x16x32_bf16(af, wa[slot][1], acc1, 0, 0, 0);
    acc2 = __builtin_amdgcn_mfma_f32_16x16x32_bf16(af, wa[slot][2], acc2, 0, 0, 0);
    acc3 = __builtin_amdgcn_mfma_f32_16x16x32_bf16(af, wa[slot][3], acc3, 0, 0, 0);
  }
#undef LOADS

  // --- epilogue: C-layout col = lane&15, row = (lane>>4)*4 + r ---
  if (which < 2) {
    short* ob = (which == 0) ? qb : kbuf;
#pragma unroll
    for (int r = 0; r < 4; ++r) {
      const size_t base = (size_t)(row0 + hi * 4 + r) * HSZ + lo;
      ob[base +  0] = f2bf(acc0[r]);
      ob[base + 16] = f2bf(acc1[r]);
      ob[base + 32] = f2bf(acc2[r]);
      ob[base + 48] = f2bf(acc3[r]);
    }
  } else {
    // vT[b][col][seq]: 4 consecutive seq rows (hi*4+r) are contiguous -> s16x4
    const int b = row0 >> 11;
    const int rloc = (row0 & (SEQ - 1)) + hi * 4;
    short* vbase = vT + (size_t)b * HSZ * SEQ + rloc;
    s16x4 p0, p1, p2, p3;
#pragma unroll
    for (int r = 0; r < 4; ++r) {
      p0[r] = f2bf(acc0[r]); p1[r] = f2bf(acc1[r]);
      p2[r] = f2bf(acc2[r]); p3[r] = f2bf(acc3[r]);
    }
    *(s16x4*)(vbase + (size_t)(lo)      * SEQ) = p0;
    *(s16x4*)(vbase + (size_t)(lo + 16) * SEQ) = p1;
    *(s16x4*)(vbase + (size_t)(lo + 32) * SEQ) = p2;
    *(s16x4*)(vbase + (size_t)(lo + 48) * SEQ) = p3;
  }
}

// ---------------- Kernel 2: causal flash attention -------------------------
// grid 1024 (one block per 16-row q-tile, heavy tiles first), block 256.
// 4 waves split the causal k-block range; flash-decoding merge in LDS.
__global__ __launch_bounds__(256) void attn(const short* __restrict__ qb,
                                            const short* __restrict__ kbuf,
                                            const short* __restrict__ vT,
                                            float* __restrict__ out) {
  __shared__ short plds[4][16 * 32];   // wave-private P staging (bf16)
  __shared__ f32x4 ored[4][16 * 17];   // o partials, f32 stride 68
  __shared__ float mred[4][16];
  __shared__ float lred[4][16];
  const int tid = threadIdx.x;
  const int wave = tid >> 6, lane = tid & 63;
  const int hi = lane >> 4, lo = lane & 15;
  const int bid = blockIdx.x;
  const int tq = 127 - (bid >> 3);    // heavy q-tiles dispatched first
  const int b  = bid & 7;
  const int q0 = tq * 16;

  const short* qp = qb + (size_t)(b * SEQ + q0 + lo) * HSZ + hi * 8;
  const bf16x8 qf0 = *(const bf16x8*)qp;
  const bf16x8 qf1 = *(const bf16x8*)(qp + 32);

  f32x4 o0 = {0.f, 0.f, 0.f, 0.f}, o1 = o0, o2 = o0, o3 = o0;
  f32x4 mrow = {-1e30f, -1e30f, -1e30f, -1e30f};
  f32x4 lrow = {0.f, 0.f, 0.f, 0.f};

  const short* kb_ = kbuf + (size_t)b * SEQ * HSZ;
  const short* vb_ = vT + (size_t)b * HSZ * SEQ;
  short* pl = plds[wave];
  const int nkb = (q0 + 47) >> 5;
  const int chunk = (nkb + 3) >> 2;
  const int kks = wave * chunk;
  const int kke = min(kks + chunk, nkb);

  for (int kk = kks; kk < kke; ++kk) {
    const int kc0 = kk * 32;
    const short* kr0 = kb_ + (size_t)(kc0 + lo) * HSZ + hi * 8;
    const short* kr1 = kr0 + 16 * HSZ;
    f32x4 s0v = {0.f, 0.f, 0.f, 0.f}, s1v = s0v;
    s0v = __builtin_amdgcn_mfma_f32_16x16x32_bf16(qf0, *(const bf16x8*)kr0, s0v, 0, 0, 0);
    s0v = __builtin_amdgcn_mfma_f32_16x16x32_bf16(qf1, *(const bf16x8*)(kr0 + 32), s0v, 0, 0, 0);
    s1v = __builtin_amdgcn_mfma_f32_16x16x32_bf16(qf0, *(const bf16x8*)kr1, s1v, 0, 0, 0);
    s1v = __builtin_amdgcn_mfma_f32_16x16x32_bf16(qf1, *(const bf16x8*)(kr1 + 32), s1v, 0, 0, 0);

    const bool edge = (kc0 + 31 > q0);
#pragma unroll
    for (int r = 0; r < 4; ++r) {
      const int row = q0 + hi * 4 + r;
      float s0 = s0v[r], s1 = s1v[r];
      if (edge) {
        if (kc0 + lo > row)      s0 = -1e30f;
        if (kc0 + 16 + lo > row) s1 = -1e30f;
      }
      float pm = fmaxf(s0, s1);
      pm = fmaxf(pm, __shfl_xor(pm, 1, 16));
      pm = fmaxf(pm, __shfl_xor(pm, 2, 16));
      pm = fmaxf(pm, __shfl_xor(pm, 4, 16));
      pm = fmaxf(pm, __shfl_xor(pm, 8, 16));
      const float mn  = fmaxf(mrow[r], pm);
      const float fac = __expf(mrow[r] - mn);
      mrow[r] = mn;
      const float p0 = __expf(s0 - mn), p1 = __expf(s1 - mn);
      float ps = p0 + p1;
      ps += __shfl_xor(ps, 1, 16);
      ps += __shfl_xor(ps, 2, 16);
      ps += __shfl_xor(ps, 4, 16);
      ps += __shfl_xor(ps, 8, 16);
      lrow[r] = lrow[r] * fac + ps;
      o0[r] *= fac; o1[r] *= fac; o2[r] *= fac; o3[r] *= fac;
      pl[(hi * 4 + r) * 32 + lo]      = f2bf(p0);
      pl[(hi * 4 + r) * 32 + 16 + lo] = f2bf(p1);
    }
    const bf16x8 pa = *(const bf16x8*)(pl + lo * 32 + hi * 8);
    const short* vr = vb_ + (size_t)lo * SEQ + kc0 + hi * 8;
    o0 = __builtin_amdgcn_mfma_f32_16x16x32_bf16(pa, *(const bf16x8*)(vr), o0, 0, 0, 0);
    o1 = __builtin_amdgcn_mfma_f32_16x16x32_bf16(pa, *(const bf16x8*)(vr + 16 * SEQ), o1, 0, 0, 0);
    o2 = __builtin_amdgcn_mfma_f32_16x16x32_bf16(pa, *(const bf16x8*)(vr + 32 * SEQ), o2, 0, 0, 0);
    o3 = __builtin_amdgcn_mfma_f32_16x16x32_bf16(pa, *(const bf16x8*)(vr + 48 * SEQ), o3, 0, 0, 0);
  }

  // partials -> LDS
  float* redf = (float*)&ored[wave][0];
#pragma unroll
  for (int r = 0; r < 4; ++r) {
    const int row = hi * 4 + r;
    redf[row * 68 + lo]      = o0[r];
    redf[row * 68 + 16 + lo] = o1[r];
    redf[row * 68 + 32 + lo] = o2[r];
    redf[row * 68 + 48 + lo] = o3[r];
  }
  if (lo == 0) {
#pragma unroll
    for (int r = 0; r < 4; ++r) {
      mred[wave][hi * 4 + r] = mrow[r];
      lred[wave][hi * 4 + r] = lrow[r];
    }
  }
  __syncthreads();

  // flash-decoding merge across the 4 k-splits
  const int row = tid >> 4, cg = tid & 15;
  float mv0 = mred[0][row], mv1 = mred[1][row], mv2 = mred[2][row], mv3 = mred[3][row];
  float M = fmaxf(fmaxf(mv0, mv1), fmaxf(mv2, mv3));
  const float w0 = __expf(mv0 - M), w1 = __expf(mv1 - M);
  const float w2 = __expf(mv2 - M), w3 = __expf(mv3 - M);
  const float L = lred[0][row] * w0 + lred[1][row] * w1 +
                  lred[2][row] * w2 + lred[3][row] * w3;
  f32x4 acc = ored[0][row * 17 + cg] * w0 + ored[1][row * 17 + cg] * w1 +
              ored[2][row * 17 + cg] * w2 + ored[3][row * 17 + cg] * w3;
  acc *= (1.0f / L);
  *(f32x4*)(out + ((size_t)(b * SEQ + q0 + row)) * HSZ + cg * 4) = acc;
}

extern "C" void kernel_launch(void* const* d_in, const int* in_sizes, int n_in,
                              void* d_out, int out_size, void* d_ws, size_t ws_size,
                              hipStream_t stream) {
  const float* query = (const float*)d_in[0];
  const float* key   = (const float*)d_in[1];
  const float* value = (const float*)d_in[2];
  const float* Wq    = (const float*)d_in[3];
  const float* Wk    = (const float*)d_in[4];
  const float* Wv    = (const float*)d_in[5];

  char* ws = (char*)d_ws;
  short* wfrag = (short*)ws;                                  // 384 KiB
  short* qb    = (short*)(ws + (3 << 17));                    // 2 MiB
  short* kb    = (short*)(ws + (3 << 17) + (1 << 21));        // 2 MiB
  short* vT    = (short*)(ws + (3 << 17) + (2 << 21));        // 2 MiB
  float* outp  = (float*)d_out;

  hipLaunchKernelGGL(w_prep, dim3(64), dim3(256), 0, stream, Wq, Wk, Wv, wfrag);
  hipLaunchKernelGGL(proj, dim3(256, 3), dim3(256), 0, stream,
                     query, key, value, wfrag, qb, kb, vT);
  hipLaunchKernelGGL(attn, dim3(1024), dim3(256), 0, stream, qb, kb, vT, outp);
}

// Round 8
// 84.499 us; speedup vs baseline: 1.0093x; 1.0093x over previous
//
#include <hip/hip_runtime.h>
#include <hip/hip_bf16.h>
#include <stdint.h>

// CrossAttentionHead: B=8,S=2048,D=1024,HS=64, fp32 in/out, bf16 MFMA internally.
// k0: W -> bf16 fragment-swizzled (scale folded into Wq)
// k1: projections — R7: inline-asm load pipeline. R1-R6: every compiler-visible
//     load structure (LDS-staged, reg-staged, gload_lds, counted-vmcnt blocks)
//     gets serialized by hipcc's scheduler (VGPR=36 proves sunk loads) ->
//     ~80us latency-bound regardless. asm volatile global_load_dwordx4 is NOT
//     tracked by the compiler's waitcnt insertion and volatile asm order is
//     preserved -> hand-built depth-3 pipeline with counted vmcnt(12/6/0).
// k2: flash attention, causal, 4-way k-split per q-tile (flash-decoding merge)

#define NB  8
#define SEQ 2048
#define DIM 1024
#define HSZ 64

typedef short bf16x8 __attribute__((ext_vector_type(8)));
typedef short s16x4  __attribute__((ext_vector_type(4)));
typedef float f32x4  __attribute__((ext_vector_type(4)));

__device__ __forceinline__ short f2bf(float f) {
  __hip_bfloat16 h = __float2bfloat16(f);
  return __builtin_bit_cast(short, h);
}

__device__ __forceinline__ void gld16f(f32x4& d, const float* p) {
  asm volatile("global_load_dwordx4 %0, %1, off" : "=v"(d) : "v"(p));
}
__device__ __forceinline__ void gld16s(bf16x8& d, const short* p) {
  asm volatile("global_load_dwordx4 %0, %1, off" : "=v"(d) : "v"(p));
}

// ---------------- Kernel 0: W -> bf16 B-fragment layout -------------------
// idx = (((w*32 + s)*4 + t)*64 + lane)*8 + i
// val = W[k][n]*scale, k = s*32 + (lane>>4)*8 + i, n = t*16 + (lane&15)
__global__ void w_prep(const float* __restrict__ Wq, const float* __restrict__ Wk,
                       const float* __restrict__ Wv, short* __restrict__ wfrag) {
  const int total = 3 << 16;
  for (int e = blockIdx.x * blockDim.x + threadIdx.x; e < total;
       e += gridDim.x * blockDim.x) {
    int i = e & 7, l = (e >> 3) & 63, t = (e >> 9) & 3, s = (e >> 11) & 31, w = e >> 16;
    const float* W = (w == 0) ? Wq : (w == 1) ? Wk : Wv;
    float scale = (w == 0) ? 0.125f : 1.0f;   // fold HS^-0.5 into Wq
    int k = s * 32 + (l >> 4) * 8 + i;
    int n = t * 16 + (l & 15);
    wfrag[e] = f2bf(W[k * HSZ + n] * scale);
  }
}

// ---------------- Kernel 1: projections -----------------------------------
// grid (256, 3), block 256 (4 waves, each wave = one independent 16x64 tile).
// K=1024 in 32 steps of 32; per step per lane: 2 f32x4 X-loads + 4 bf16x8
// W-frag loads (all asm) + 4 MFMA. Depth-3 rotation: loads issue 2 steps
// ahead; steady-state wait = vmcnt(12). No LDS, no barriers.
__global__ __launch_bounds__(256) void proj(const float* __restrict__ Xq,
                                            const float* __restrict__ Xk,
                                            const float* __restrict__ Xv,
                                            const short* __restrict__ wfrag,
                                            short* __restrict__ qb,
                                            short* __restrict__ kbuf,
                                            short* __restrict__ vT) {
  const int tid = threadIdx.x;
  const int wave = tid >> 6, lane = tid & 63;
  const int hi = lane >> 4, lo = lane & 15;
  const int which = blockIdx.y;
  const float* X = (which == 0) ? Xq : (which == 1) ? Xk : Xv;
  const short* wf = wfrag + (which << 16);
  const int row0 = (blockIdx.x * 4 + wave) * 16;
  const float* xp = X + (size_t)(row0 + lo) * DIM + hi * 8;
  const short* wp = wf + lane * 8;

  f32x4  xa[3][2];
  bf16x8 wa[3][4];

#define LOADS(s, slot)                                                         \
  {                                                                            \
    gld16f(xa[slot][0], xp + (s) * 32);                                        \
    gld16f(xa[slot][1], xp + (s) * 32 + 4);                                    \
    const short* wbp = wp + (s) * 2048;                                        \
    gld16s(wa[slot][0], wbp);                                                  \
    gld16s(wa[slot][1], wbp + 512);                                            \
    gld16s(wa[slot][2], wbp + 1024);                                           \
    gld16s(wa[slot][3], wbp + 1536);                                           \
  }

  LOADS(0, 0);      // outstanding: 6
  LOADS(1, 1);      // outstanding: 12

  f32x4 acc0 = {0.f, 0.f, 0.f, 0.f}, acc1 = acc0, acc2 = acc0, acc3 = acc0;
#pragma unroll
  for (int s = 0; s < 32; ++s) {
    const int slot = s % 3;
    if (s < 30) LOADS(s + 2, (s + 2) % 3);               // outstanding: 18
    // wait for step s's 6 loads; keep the 12 newer ones in flight
    if (s < 30)       asm volatile("s_waitcnt vmcnt(12)" ::: "memory");
    else if (s == 30) asm volatile("s_waitcnt vmcnt(6)" ::: "memory");
    else              asm volatile("s_waitcnt vmcnt(0)" ::: "memory");
    __builtin_amdgcn_sched_barrier(0);   // rule #18: MFMA must not hoist past wait
    const f32x4 a0 = xa[slot][0];
    const f32x4 a1 = xa[slot][1];
    bf16x8 af;
    af[0] = f2bf(a0[0]); af[1] = f2bf(a0[1]); af[2] = f2bf(a0[2]); af[3] = f2bf(a0[3]);
    af[4] = f2bf(a1[0]); af[5] = f2bf(a1[1]); af[6] = f2bf(a1[2]); af[7] = f2bf(a1[3]);
    acc0 = __builtin_amdgcn_mfma_f32_16x16x32_bf16(af, wa[slot][0], acc0, 0, 0, 0);
    acc1 = __builtin_amdgcn_mfma_f32_16x16x32_bf16(af, wa[slot][1], acc1, 0, 0, 0);
    acc2 = __builtin_amdgcn_mfma_f32_16x16x32_bf16(af, wa[slot][2], acc2, 0, 0, 0);
    acc3 = __builtin_amdgcn_mfma_f32_16x16x32_bf16(af, wa[slot][3], acc3, 0, 0, 0);
  }
#undef LOADS

  // --- epilogue: C-layout col = lane&15, row = (lane>>4)*4 + r ---
  if (which < 2) {
    short* ob = (which == 0) ? qb : kbuf;
#pragma unroll
    for (int r = 0; r < 4; ++r) {
      const size_t base = (size_t)(row0 + hi * 4 + r) * HSZ + lo;
      ob[base +  0] = f2bf(acc0[r]);
      ob[base + 16] = f2bf(acc1[r]);
      ob[base + 32] = f2bf(acc2[r]);
      ob[base + 48] = f2bf(acc3[r]);
    }
  } else {
    // vT[b][col][seq]: 4 consecutive seq rows (hi*4+r) are contiguous -> s16x4
    const int b = row0 >> 11;
    const int rloc = (row0 & (SEQ - 1)) + hi * 4;
    short* vbase = vT + (size_t)b * HSZ * SEQ + rloc;
    s16x4 p0, p1, p2, p3;
#pragma unroll
    for (int r = 0; r < 4; ++r) {
      p0[r] = f2bf(acc0[r]); p1[r] = f2bf(acc1[r]);
      p2[r] = f2bf(acc2[r]); p3[r] = f2bf(acc3[r]);
    }
    *(s16x4*)(vbase + (size_t)(lo)      * SEQ) = p0;
    *(s16x4*)(vbase + (size_t)(lo + 16) * SEQ) = p1;
    *(s16x4*)(vbase + (size_t)(lo + 32) * SEQ) = p2;
    *(s16x4*)(vbase + (size_t)(lo + 48) * SEQ) = p3;
  }
}

// ---------------- Kernel 2: causal flash attention -------------------------
// grid 1024 (one block per 16-row q-tile, heavy tiles first), block 256.
// 4 waves split the causal k-block range; flash-decoding merge in LDS.
__global__ __launch_bounds__(256) void attn(const short* __restrict__ qb,
                                            const short* __restrict__ kbuf,
                                            const short* __restrict__ vT,
                                            float* __restrict__ out) {
  __shared__ short plds[4][16 * 32];   // wave-private P staging (bf16)
  __shared__ f32x4 ored[4][16 * 17];   // o partials, f32 stride 68
  __shared__ float mred[4][16];
  __shared__ float lred[4][16];
  const int tid = threadIdx.x;
  const int wave = tid >> 6, lane = tid & 63;
  const int hi = lane >> 4, lo = lane & 15;
  const int bid = blockIdx.x;
  const int tq = 127 - (bid >> 3);    // heavy q-tiles dispatched first
  const int b  = bid & 7;
  const int q0 = tq * 16;

  const short* qp = qb + (size_t)(b * SEQ + q0 + lo) * HSZ + hi * 8;
  const bf16x8 qf0 = *(const bf16x8*)qp;
  const bf16x8 qf1 = *(const bf16x8*)(qp + 32);

  f32x4 o0 = {0.f, 0.f, 0.f, 0.f}, o1 = o0, o2 = o0, o3 = o0;
  f32x4 mrow = {-1e30f, -1e30f, -1e30f, -1e30f};
  f32x4 lrow = {0.f, 0.f, 0.f, 0.f};

  const short* kb_ = kbuf + (size_t)b * SEQ * HSZ;
  const short* vb_ = vT + (size_t)b * HSZ * SEQ;
  short* pl = plds[wave];
  const int nkb = (q0 + 47) >> 5;
  const int chunk = (nkb + 3) >> 2;
  const int kks = wave * chunk;
  const int kke = min(kks + chunk, nkb);

  for (int kk = kks; kk < kke; ++kk) {
    const int kc0 = kk * 32;
    const short* kr0 = kb_ + (size_t)(kc0 + lo) * HSZ + hi * 8;
    const short* kr1 = kr0 + 16 * HSZ;
    f32x4 s0v = {0.f, 0.f, 0.f, 0.f}, s1v = s0v;
    s0v = __builtin_amdgcn_mfma_f32_16x16x32_bf16(qf0, *(const bf16x8*)kr0, s0v, 0, 0, 0);
    s0v = __builtin_amdgcn_mfma_f32_16x16x32_bf16(qf1, *(const bf16x8*)(kr0 + 32), s0v, 0, 0, 0);
    s1v = __builtin_amdgcn_mfma_f32_16x16x32_bf16(qf0, *(const bf16x8*)kr1, s1v, 0, 0, 0);
    s1v = __builtin_amdgcn_mfma_f32_16x16x32_bf16(qf1, *(const bf16x8*)(kr1 + 32), s1v, 0, 0, 0);

    const bool edge = (kc0 + 31 > q0);
#pragma unroll
    for (int r = 0; r < 4; ++r) {
      const int row = q0 + hi * 4 + r;
      float s0 = s0v[r], s1 = s1v[r];
      if (edge) {
        if (kc0 + lo > row)      s0 = -1e30f;
        if (kc0 + 16 + lo > row) s1 = -1e30f;
      }
      float pm = fmaxf(s0, s1);
      pm = fmaxf(pm, __shfl_xor(pm, 1, 16));
      pm = fmaxf(pm, __shfl_xor(pm, 2, 16));
      pm = fmaxf(pm, __shfl_xor(pm, 4, 16));
      pm = fmaxf(pm, __shfl_xor(pm, 8, 16));
      const float mn  = fmaxf(mrow[r], pm);
      const float fac = __expf(mrow[r] - mn);
      mrow[r] = mn;
      const float p0 = __expf(s0 - mn), p1 = __expf(s1 - mn);
      float ps = p0 + p1;
      ps += __shfl_xor(ps, 1, 16);
      ps += __shfl_xor(ps, 2, 16);
      ps += __shfl_xor(ps, 4, 16);
      ps += __shfl_xor(ps, 8, 16);
      lrow[r] = lrow[r] * fac + ps;
      o0[r] *= fac; o1[r] *= fac; o2[r] *= fac; o3[r] *= fac;
      pl[(hi * 4 + r) * 32 + lo]      = f2bf(p0);
      pl[(hi * 4 + r) * 32 + 16 + lo] = f2bf(p1);
    }
    const bf16x8 pa = *(const bf16x8*)(pl + lo * 32 + hi * 8);
    const short* vr = vb_ + (size_t)lo * SEQ + kc0 + hi * 8;
    o0 = __builtin_amdgcn_mfma_f32_16x16x32_bf16(pa, *(const bf16x8*)(vr), o0, 0, 0, 0);
    o1 = __builtin_amdgcn_mfma_f32_16x16x32_bf16(pa, *(const bf16x8*)(vr + 16 * SEQ), o1, 0, 0, 0);
    o2 = __builtin_amdgcn_mfma_f32_16x16x32_bf16(pa, *(const bf16x8*)(vr + 32 * SEQ), o2, 0, 0, 0);
    o3 = __builtin_amdgcn_mfma_f32_16x16x32_bf16(pa, *(const bf16x8*)(vr + 48 * SEQ), o3, 0, 0, 0);
  }

  // partials -> LDS
  float* redf = (float*)&ored[wave][0];
#pragma unroll
  for (int r = 0; r < 4; ++r) {
    const int row = hi * 4 + r;
    redf[row * 68 + lo]      = o0[r];
    redf[row * 68 + 16 + lo] = o1[r];
    redf[row * 68 + 32 + lo] = o2[r];
    redf[row * 68 + 48 + lo] = o3[r];
  }
  if (lo == 0) {
#pragma unroll
    for (int r = 0; r < 4; ++r) {
      mred[wave][hi * 4 + r] = mrow[r];
      lred[wave][hi * 4 + r] = lrow[r];
    }
  }
  __syncthreads();

  // flash-decoding merge across the 4 k-splits
  const int row = tid >> 4, cg = tid & 15;
  float mv0 = mred[0][row], mv1 = mred[1][row], mv2 = mred[2][row], mv3 = mred[3][row];
  float M = fmaxf(fmaxf(mv0, mv1), fmaxf(mv2, mv3));
  const float w0 = __expf(mv0 - M), w1 = __expf(mv1 - M);
  const float w2 = __expf(mv2 - M), w3 = __expf(mv3 - M);
  const float L = lred[0][row] * w0 + lred[1][row] * w1 +
                  lred[2][row] * w2 + lred[3][row] * w3;
  f32x4 acc = ored[0][row * 17 + cg] * w0 + ored[1][row * 17 + cg] * w1 +
              ored[2][row * 17 + cg] * w2 + ored[3][row * 17 + cg] * w3;
  acc *= (1.0f / L);
  *(f32x4*)(out + ((size_t)(b * SEQ + q0 + row)) * HSZ + cg * 4) = acc;
}

extern "C" void kernel_launch(void* const* d_in, const int* in_sizes, int n_in,
                              void* d_out, int out_size, void* d_ws, size_t ws_size,
                              hipStream_t stream) {
  const float* query = (const float*)d_in[0];
  const float* key   = (const float*)d_in[1];
  const float* value = (const float*)d_in[2];
  const float* Wq    = (const float*)d_in[3];
  const float* Wk    = (const float*)d_in[4];
  const float* Wv    = (const float*)d_in[5];

  char* ws = (char*)d_ws;
  short* wfrag = (short*)ws;                                  // 384 KiB
  short* qb    = (short*)(ws + (3 << 17));                    // 2 MiB
  short* kb    = (short*)(ws + (3 << 17) + (1 << 21));        // 2 MiB
  short* vT    = (short*)(ws + (3 << 17) + (2 << 21));        // 2 MiB
  float* outp  = (float*)d_out;

  hipLaunchKernelGGL(w_prep, dim3(64), dim3(256), 0, stream, Wq, Wk, Wv, wfrag);
  hipLaunchKernelGGL(proj, dim3(256, 3), dim3(256), 0, stream,
                     query, key, value, wfrag, qb, kb, vT);
  hipLaunchKernelGGL(attn, dim3(1024), dim3(256), 0, stream, qb, kb, vT, outp);
}

// Round 10
// 84.492 us; speedup vs baseline: 1.0094x; 1.0001x over previous
//
#include <hip/hip_runtime.h>
#include <hip/hip_bf16.h>
#include <stdint.h>

// CrossAttentionHead: B=8,S=2048,D=1024,HS=64, fp32 in/out, bf16 MFMA internally.
// k0: W -> bf16 fragment-swizzled (scale folded into Wq)
// k1: projections — R8/R9: asm-load pipeline with NAMED registers. R7's arrays
//     were scratch-backed (VGPR=52 < the 72 needed for 18 in-flight loads),
//     forcing an implicit wait per load -> serial. Named vector variables +
//     hand-rotated 3-slot schedule eliminate scratch; volatile asm pins order;
//     counted vmcnt(12/6/0) keeps 12-18 loads in flight per wave.
//     (R9 fixes the macro-arity compile error via variadic indirection.)
// k2: flash attention, causal, 4-way k-split per q-tile (flash-decoding merge)

#define NB  8
#define SEQ 2048
#define DIM 1024
#define HSZ 64

typedef short bf16x8 __attribute__((ext_vector_type(8)));
typedef short s16x4  __attribute__((ext_vector_type(4)));
typedef float f32x4  __attribute__((ext_vector_type(4)));

__device__ __forceinline__ short f2bf(float f) {
  __hip_bfloat16 h = __float2bfloat16(f);
  return __builtin_bit_cast(short, h);
}

__device__ __forceinline__ void gld16f(f32x4& d, const float* p) {
  asm volatile("global_load_dwordx4 %0, %1, off" : "=v"(d) : "v"(p));
}
__device__ __forceinline__ void gld16s(bf16x8& d, const short* p) {
  asm volatile("global_load_dwordx4 %0, %1, off" : "=v"(d) : "v"(p));
}

// ---------------- Kernel 0: W -> bf16 B-fragment layout -------------------
// idx = (((w*32 + s)*4 + t)*64 + lane)*8 + i
// val = W[k][n]*scale, k = s*32 + (lane>>4)*8 + i, n = t*16 + (lane&15)
__global__ void w_prep(const float* __restrict__ Wq, const float* __restrict__ Wk,
                       const float* __restrict__ Wv, short* __restrict__ wfrag) {
  const int total = 3 << 16;
  for (int e = blockIdx.x * blockDim.x + threadIdx.x; e < total;
       e += gridDim.x * blockDim.x) {
    int i = e & 7, l = (e >> 3) & 63, t = (e >> 9) & 3, s = (e >> 11) & 31, w = e >> 16;
    const float* W = (w == 0) ? Wq : (w == 1) ? Wk : Wv;
    float scale = (w == 0) ? 0.125f : 1.0f;   // fold HS^-0.5 into Wq
    int k = s * 32 + (l >> 4) * 8 + i;
    int n = t * 16 + (l & 15);
    wfrag[e] = f2bf(W[k * HSZ + n] * scale);
  }
}

// ---------------- Kernel 1: projections -----------------------------------
// grid (256, 3), block 256 (4 waves, each wave = one independent 16x64 tile).
// K=1024 in 32 steps of 32; per step per lane: 2 f32x4 X-loads + 4 bf16x8
// W-frag loads (asm, named dests) + 4 MFMA. 3-slot rotation, loads issue 2
// steps ahead; steady-state wait vmcnt(12). No LDS, no barriers, no arrays.
__global__ __launch_bounds__(256) void proj(const float* __restrict__ Xq,
                                            const float* __restrict__ Xk,
                                            const float* __restrict__ Xv,
                                            const short* __restrict__ wfrag,
                                            short* __restrict__ qb,
                                            short* __restrict__ kbuf,
                                            short* __restrict__ vT) {
  const int tid = threadIdx.x;
  const int wave = tid >> 6, lane = tid & 63;
  const int hi = lane >> 4, lo = lane & 15;
  const int which = blockIdx.y;
  const float* X = (which == 0) ? Xq : (which == 1) ? Xk : Xv;
  const short* wf = wfrag + (which << 16);
  const int row0 = (blockIdx.x * 4 + wave) * 16;
  const float* xp = X + (size_t)(row0 + lo) * DIM + hi * 8;
  const short* wp = wf + lane * 8;

  f32x4  xA0, xA1, xB0, xB1, xC0, xC1;
  bf16x8 wA0, wA1, wA2, wA3, wB0, wB1, wB2, wB3, wC0, wC1, wC2, wC3;
  f32x4 acc0 = {0.f, 0.f, 0.f, 0.f}, acc1 = acc0, acc2 = acc0, acc3 = acc0;

#define LOADS_IMPL(s, X0, X1, W0, W1, W2, W3)                                  \
  do {                                                                         \
    gld16f(X0, xp + (s) * 32);                                                 \
    gld16f(X1, xp + (s) * 32 + 4);                                             \
    const short* wbp_ = wp + (s) * 2048;                                       \
    gld16s(W0, wbp_);                                                          \
    gld16s(W1, wbp_ + 512);                                                    \
    gld16s(W2, wbp_ + 1024);                                                   \
    gld16s(W3, wbp_ + 1536);                                                   \
  } while (0)

#define COMPUTE_IMPL(X0, X1, W0, W1, W2, W3)                                   \
  do {                                                                         \
    bf16x8 af_;                                                                \
    af_[0] = f2bf(X0[0]); af_[1] = f2bf(X0[1]);                                \
    af_[2] = f2bf(X0[2]); af_[3] = f2bf(X0[3]);                                \
    af_[4] = f2bf(X1[0]); af_[5] = f2bf(X1[1]);                                \
    af_[6] = f2bf(X1[2]); af_[7] = f2bf(X1[3]);                                \
    acc0 = __builtin_amdgcn_mfma_f32_16x16x32_bf16(af_, W0, acc0, 0, 0, 0);    \
    acc1 = __builtin_amdgcn_mfma_f32_16x16x32_bf16(af_, W1, acc1, 0, 0, 0);    \
    acc2 = __builtin_amdgcn_mfma_f32_16x16x32_bf16(af_, W2, acc2, 0, 0, 0);    \
    acc3 = __builtin_amdgcn_mfma_f32_16x16x32_bf16(af_, W3, acc3, 0, 0, 0);    \
  } while (0)

// variadic indirection: SA/SB/SC expand to 6 args during rescan
#define LOADS(s, ...)  LOADS_IMPL(s, __VA_ARGS__)
#define COMPUTE(...)   COMPUTE_IMPL(__VA_ARGS__)

#define VMW(n)                                                                 \
  do {                                                                         \
    asm volatile("s_waitcnt vmcnt(" #n ")" ::: "memory");                      \
    __builtin_amdgcn_sched_barrier(0);                                         \
  } while (0)

#define SA xA0, xA1, wA0, wA1, wA2, wA3
#define SB xB0, xB1, wB0, wB1, wB2, wB3
#define SC xC0, xC1, wC0, wC1, wC2, wC3

  LOADS(0, SA);                       // outstanding: 6
  LOADS(1, SB);                       // outstanding: 12

  for (int t = 0; t < 30; t += 3) {   // computes steps t, t+1, t+2
    LOADS(t + 2, SC); VMW(12); COMPUTE(SA);
    LOADS(t + 3, SA); VMW(12); COMPUTE(SB);
    LOADS(t + 4, SB); VMW(12); COMPUTE(SC);
  }
  VMW(6);  COMPUTE(SA);               // step 30
  VMW(0);  COMPUTE(SB);               // step 31

#undef LOADS
#undef COMPUTE
#undef LOADS_IMPL
#undef COMPUTE_IMPL
#undef VMW
#undef SA
#undef SB
#undef SC

  // --- epilogue: C-layout col = lane&15, row = (lane>>4)*4 + r ---
  if (which < 2) {
    short* ob = (which == 0) ? qb : kbuf;
#pragma unroll
    for (int r = 0; r < 4; ++r) {
      const size_t base = (size_t)(row0 + hi * 4 + r) * HSZ + lo;
      ob[base +  0] = f2bf(acc0[r]);
      ob[base + 16] = f2bf(acc1[r]);
      ob[base + 32] = f2bf(acc2[r]);
      ob[base + 48] = f2bf(acc3[r]);
    }
  } else {
    // vT[b][col][seq]: 4 consecutive seq rows (hi*4+r) are contiguous -> s16x4
    const int b = row0 >> 11;
    const int rloc = (row0 & (SEQ - 1)) + hi * 4;
    short* vbase = vT + (size_t)b * HSZ * SEQ + rloc;
    s16x4 p0, p1, p2, p3;
#pragma unroll
    for (int r = 0; r < 4; ++r) {
      p0[r] = f2bf(acc0[r]); p1[r] = f2bf(acc1[r]);
      p2[r] = f2bf(acc2[r]); p3[r] = f2bf(acc3[r]);
    }
    *(s16x4*)(vbase + (size_t)(lo)      * SEQ) = p0;
    *(s16x4*)(vbase + (size_t)(lo + 16) * SEQ) = p1;
    *(s16x4*)(vbase + (size_t)(lo + 32) * SEQ) = p2;
    *(s16x4*)(vbase + (size_t)(lo + 48) * SEQ) = p3;
  }
}

// ---------------- Kernel 2: causal flash attention -------------------------
// grid 1024 (one block per 16-row q-tile, heavy tiles first), block 256.
// 4 waves split the causal k-block range; flash-decoding merge in LDS.
__global__ __launch_bounds__(256) void attn(const short* __restrict__ qb,
                                            const short* __restrict__ kbuf,
                                            const short* __restrict__ vT,
                                            float* __restrict__ out) {
  __shared__ short plds[4][16 * 32];   // wave-private P staging (bf16)
  __shared__ f32x4 ored[4][16 * 17];   // o partials, f32 stride 68
  __shared__ float mred[4][16];
  __shared__ float lred[4][16];
  const int tid = threadIdx.x;
  const int wave = tid >> 6, lane = tid & 63;
  const int hi = lane >> 4, lo = lane & 15;
  const int bid = blockIdx.x;
  const int tq = 127 - (bid >> 3);    // heavy q-tiles dispatched first
  const int b  = bid & 7;
  const int q0 = tq * 16;

  const short* qp = qb + (size_t)(b * SEQ + q0 + lo) * HSZ + hi * 8;
  const bf16x8 qf0 = *(const bf16x8*)qp;
  const bf16x8 qf1 = *(const bf16x8*)(qp + 32);

  f32x4 o0 = {0.f, 0.f, 0.f, 0.f}, o1 = o0, o2 = o0, o3 = o0;
  f32x4 mrow = {-1e30f, -1e30f, -1e30f, -1e30f};
  f32x4 lrow = {0.f, 0.f, 0.f, 0.f};

  const short* kb_ = kbuf + (size_t)b * SEQ * HSZ;
  const short* vb_ = vT + (size_t)b * HSZ * SEQ;
  short* pl = plds[wave];
  const int nkb = (q0 + 47) >> 5;
  const int chunk = (nkb + 3) >> 2;
  const int kks = wave * chunk;
  const int kke = min(kks + chunk, nkb);

  for (int kk = kks; kk < kke; ++kk) {
    const int kc0 = kk * 32;
    const short* kr0 = kb_ + (size_t)(kc0 + lo) * HSZ + hi * 8;
    const short* kr1 = kr0 + 16 * HSZ;
    f32x4 s0v = {0.f, 0.f, 0.f, 0.f}, s1v = s0v;
    s0v = __builtin_amdgcn_mfma_f32_16x16x32_bf16(qf0, *(const bf16x8*)kr0, s0v, 0, 0, 0);
    s0v = __builtin_amdgcn_mfma_f32_16x16x32_bf16(qf1, *(const bf16x8*)(kr0 + 32), s0v, 0, 0, 0);
    s1v = __builtin_amdgcn_mfma_f32_16x16x32_bf16(qf0, *(const bf16x8*)kr1, s1v, 0, 0, 0);
    s1v = __builtin_amdgcn_mfma_f32_16x16x32_bf16(qf1, *(const bf16x8*)(kr1 + 32), s1v, 0, 0, 0);

    const bool edge = (kc0 + 31 > q0);
#pragma unroll
    for (int r = 0; r < 4; ++r) {
      const int row = q0 + hi * 4 + r;
      float s0 = s0v[r], s1 = s1v[r];
      if (edge) {
        if (kc0 + lo > row)      s0 = -1e30f;
        if (kc0 + 16 + lo > row) s1 = -1e30f;
      }
      float pm = fmaxf(s0, s1);
      pm = fmaxf(pm, __shfl_xor(pm, 1, 16));
      pm = fmaxf(pm, __shfl_xor(pm, 2, 16));
      pm = fmaxf(pm, __shfl_xor(pm, 4, 16));
      pm = fmaxf(pm, __shfl_xor(pm, 8, 16));
      const float mn  = fmaxf(mrow[r], pm);
      const float fac = __expf(mrow[r] - mn);
      mrow[r] = mn;
      const float p0 = __expf(s0 - mn), p1 = __expf(s1 - mn);
      float ps = p0 + p1;
      ps += __shfl_xor(ps, 1, 16);
      ps += __shfl_xor(ps, 2, 16);
      ps += __shfl_xor(ps, 4, 16);
      ps += __shfl_xor(ps, 8, 16);
      lrow[r] = lrow[r] * fac + ps;
      o0[r] *= fac; o1[r] *= fac; o2[r] *= fac; o3[r] *= fac;
      pl[(hi * 4 + r) * 32 + lo]      = f2bf(p0);
      pl[(hi * 4 + r) * 32 + 16 + lo] = f2bf(p1);
    }
    const bf16x8 pa = *(const bf16x8*)(pl + lo * 32 + hi * 8);
    const short* vr = vb_ + (size_t)lo * SEQ + kc0 + hi * 8;
    o0 = __builtin_amdgcn_mfma_f32_16x16x32_bf16(pa, *(const bf16x8*)(vr), o0, 0, 0, 0);
    o1 = __builtin_amdgcn_mfma_f32_16x16x32_bf16(pa, *(const bf16x8*)(vr + 16 * SEQ), o1, 0, 0, 0);
    o2 = __builtin_amdgcn_mfma_f32_16x16x32_bf16(pa, *(const bf16x8*)(vr + 32 * SEQ), o2, 0, 0, 0);
    o3 = __builtin_amdgcn_mfma_f32_16x16x32_bf16(pa, *(const bf16x8*)(vr + 48 * SEQ), o3, 0, 0, 0);
  }

  // partials -> LDS
  float* redf = (float*)&ored[wave][0];
#pragma unroll
  for (int r = 0; r < 4; ++r) {
    const int row = hi * 4 + r;
    redf[row * 68 + lo]      = o0[r];
    redf[row * 68 + 16 + lo] = o1[r];
    redf[row * 68 + 32 + lo] = o2[r];
    redf[row * 68 + 48 + lo] = o3[r];
  }
  if (lo == 0) {
#pragma unroll
    for (int r = 0; r < 4; ++r) {
      mred[wave][hi * 4 + r] = mrow[r];
      lred[wave][hi * 4 + r] = lrow[r];
    }
  }
  __syncthreads();

  // flash-decoding merge across the 4 k-splits
  const int row = tid >> 4, cg = tid & 15;
  float mv0 = mred[0][row], mv1 = mred[1][row], mv2 = mred[2][row], mv3 = mred[3][row];
  float M = fmaxf(fmaxf(mv0, mv1), fmaxf(mv2, mv3));
  const float w0 = __expf(mv0 - M), w1 = __expf(mv1 - M);
  const float w2 = __expf(mv2 - M), w3 = __expf(mv3 - M);
  const float L = lred[0][row] * w0 + lred[1][row] * w1 +
                  lred[2][row] * w2 + lred[3][row] * w3;
  f32x4 acc = ored[0][row * 17 + cg] * w0 + ored[1][row * 17 + cg] * w1 +
              ored[2][row * 17 + cg] * w2 + ored[3][row * 17 + cg] * w3;
  acc *= (1.0f / L);
  *(f32x4*)(out + ((size_t)(b * SEQ + q0 + row)) * HSZ + cg * 4) = acc;
}

extern "C" void kernel_launch(void* const* d_in, const int* in_sizes, int n_in,
                              void* d_out, int out_size, void* d_ws, size_t ws_size,
                              hipStream_t stream) {
  const float* query = (const float*)d_in[0];
  const float* key   = (const float*)d_in[1];
  const float* value = (const float*)d_in[2];
  const float* Wq    = (const float*)d_in[3];
  const float* Wk    = (const float*)d_in[4];
  const float* Wv    = (const float*)d_in[5];

  char* ws = (char*)d_ws;
  short* wfrag = (short*)ws;                                  // 384 KiB
  short* qb    = (short*)(ws + (3 << 17));                    // 2 MiB
  short* kb    = (short*)(ws + (3 << 17) + (1 << 21));        // 2 MiB
  short* vT    = (short*)(ws + (3 << 17) + (2 << 21));        // 2 MiB
  float* outp  = (float*)d_out;

  hipLaunchKernelGGL(w_prep, dim3(64), dim3(256), 0, stream, Wq, Wk, Wv, wfrag);
  hipLaunchKernelGGL(proj, dim3(256, 3), dim3(256), 0, stream,
                     query, key, value, wfrag, qb, kb, vT);
  hipLaunchKernelGGL(attn, dim3(1024), dim3(256), 0, stream, qb, kb, vT, outp);
}